// Round 16
// baseline (203.856 us; speedup 1.0000x reference)
//
#include <hip/hip_runtime.h>

// LSTM_52922587021316 — Round 19: wave role-split (L0 waves ∥ L1 waves).
// R18: DS write batching neutral, conflicts x10 with no dur change — DS is
// not the critical path. Remaining 34us stall: all waves run identical
// streams in lockstep -> serial phases align, issue port idles (occupancy
// can't fix; confirmed R6/R12/R15). T5-mechanism fix: ROLE-SPLIT. Pair
// waves: role-0 computes layer 0 (own c1/h1 recurrence, independent),
// role-1 computes layer 1 for the same 16 seqs; h1(t) crosses via a
// double-buffered LDS slot, ONE barrier per t. Window between barriers:
// workA(t+1) [role 0] overlaps workB(t) [role 1]; different instruction
// mixes per SIMD (role = wave>>2 -> one of each per SIMD) break lockstep.
// Register discipline: shared carried names (Acur, cv) across roles; L0's
// MFMAs at window start (nothing extra live across barriers); target <=60.
// Math = R15 verbatim per layer (mfma with Acur=0 at t=0 is exact) ->
// absmax identical. LDS 41728 -> 3 blocks/CU = 24 waves/CU (>= ~14 satur).
// Tripwires: VGPR>64, WRITE>2MB, occ<30%.

#define HID 32
#define TSTEPS 7
#define LSTRIDE 36   // halves per LDS h-row: 32 + 4 pad (72 B)

typedef _Float16 half8 __attribute__((ext_vector_type(8)));
typedef float floatx4 __attribute__((ext_vector_type(4)));
typedef float floatx2 __attribute__((ext_vector_type(2)));

#define LOG2E 1.44269504088896f

__device__ __forceinline__ float fast_rcp(float x) { return __builtin_amdgcn_rcpf(x); }

__device__ __forceinline__ float exp2_fast(float x) {
#if __has_builtin(__builtin_amdgcn_exp2f)
    return __builtin_amdgcn_exp2f(x);
#else
    return __expf(x * 0.69314718055994531f);
#endif
}

__device__ __forceinline__ floatx2 mk2(float a, float b) {
    floatx2 v; v[0] = a; v[1] = b; return v;
}
__device__ __forceinline__ floatx2 exp2_v2(floatx2 a) {
    return mk2(exp2_fast(a[0]), exp2_fast(a[1]));
}

// v2.5 cell update on an h-pair (R15's proven form, absmax 9.77e-4):
// Rb/Rm/Rh pair-batched, c-recurrence sum structure untouched.
__device__ __forceinline__ floatx2 cell_pair(floatx2 gi, floatx2 gf,
                                             floatx2 gg, floatx2 go,
                                             floatx2& cst) {
    const floatx2 one = mk2(1.0f, 1.0f);
    const floatx2 Ea = exp2_v2(gi);
    const floatx2 Db = exp2_v2(gf) + one;
    const floatx2 Ed = exp2_v2(gg);
    const floatx2 Ee = exp2_v2(go);
    const floatx2 M  = (Ea + one) * (Ed + one);
    const float Rb = fast_rcp(Db[0] * Db[1]);
    const float Rm = fast_rcp(M[0] * M[1]);
    const floatx2 ff  = mk2(Rb, Rb) * mk2(Db[1], Db[0]);
    const floatx2 rig = mk2(Rm, Rm) * mk2(M[1], M[0]);
    const floatx2 ig  = __builtin_elementwise_fma(Ed, rig, -rig);
    const floatx2 c   = __builtin_elementwise_fma(ff, cst, ig);
    cst = c;
    const floatx2 Ec  = exp2_v2(c * mk2(2.0f * LOG2E, 2.0f * LOG2E));
    const floatx2 Dh  = (Ee + one) * (Ec + one);
    const float Rh = fast_rcp(Dh[0] * Dh[1]);
    const floatx2 th = mk2(Rh, Rh) * mk2(Dh[1], Dh[0]);
    return __builtin_elementwise_fma(Ec, th, -th);
}

__global__ __launch_bounds__(512, 2) void lstm2_mfma(
    const float* __restrict__ xin,   // [B, 7]
    const float* __restrict__ Wih0,  // [128, 1]
    const float* __restrict__ Whh0,  // [128, 32]
    const float* __restrict__ bih0,  // [128]
    const float* __restrict__ bhh0,  // [128]
    const float* __restrict__ Wih1,  // [128, 32]
    const float* __restrict__ Whh1,  // [128, 32]
    const float* __restrict__ bih1,  // [128]
    const float* __restrict__ bhh1,  // [128]
    const float* __restrict__ fcw,   // [32]
    const float* __restrict__ fcb,   // [1]
    const float* __restrict__ fc1w,  // [7]
    const float* __restrict__ fc1b,  // [1]
    float* __restrict__ out,         // [B]
    int B)
{
    const int lane = threadIdx.x & 63;
    const int wave = threadIdx.x >> 6;
    const int pair = wave & 3;           // 4 seq-groups per block
    const int role = wave >> 2;          // 0 = layer-0 wave, 1 = layer-1 wave
    const int col  = lane & 15;          // C col / A row m
    const int rg   = lane >> 4;          // C rows rg*4..+3 / A k-chunk rg*8..+7
    const int seq_base = (blockIdx.x * 4 + pair) * 16;

    // Weight fragments, block-shared, per-lane order:
    // matrix m in {0:Whh0, 1:Wih1, 2:Whh1}, tile nt (0..7), lane, 8 halves.
    __shared__ __align__(16) _Float16 ldsw[3 * 8 * 64 * 8];       // 24 KiB
    __shared__ __align__(16) floatx2  ldsbw0[128];                // 1 KiB
    __shared__ float                  ldsb1[128];                 // 0.5 KiB
    __shared__ __align__(16) _Float16 ldsh1[4][2][16 * LSTRIDE];  // h1 handoff, dbuf
    __shared__ __align__(16) _Float16 ldsh2[4][16 * LSTRIDE];     // h2 private
    __shared__ __align__(16) float    ldsx[4][TSTEPS * 16];

    float* xl = &ldsx[pair][0];
    _Float16* h2l = &ldsh2[pair][0];

    // ---- stage x (role-0 wave of each pair) ------------------------------
    if (role == 0) {
#pragma unroll
        for (int e = lane; e < TSTEPS * 16; e += 64) {
            const int s = e / TSTEPS;
            const int tt = e - s * TSTEPS;
            xl[tt * 16 + s] = xin[seq_base * TSTEPS + e];
        }
    }

    // ---- stage prescaled weights/biases into LDS (once per block) --------
    if (wave < 3) {
        const float* Wsrc = (wave == 0) ? Whh0 : (wave == 1) ? Wih1 : Whh1;
#pragma unroll
        for (int nt = 0; nt < 8; ++nt) {
            const int n = nt * 16 + col;
            const float sc = ((n >> 5) == 2) ? (2.0f * LOG2E) : (-LOG2E);
            const float* s = Wsrc + n * HID + rg * 8;
            half8 f;
#pragma unroll
            for (int j = 0; j < 8; ++j) f[j] = (_Float16)(sc * s[j]);
            *(half8*)&ldsw[((wave * 8 + nt) * 64 + lane) * 8] = f;
        }
    } else if (wave == 3) {
#pragma unroll
        for (int i = 0; i < 2; ++i) {
            const int n = i * 64 + lane;
            const float sc = ((n >> 5) == 2) ? (2.0f * LOG2E) : (-LOG2E);
            floatx2 bw;
            bw[0] = sc * (bih0[n] + bhh0[n]);   // prescaled layer-0 bias
            bw[1] = sc * Wih0[n];               // prescaled rank-1 x weight
            ldsbw0[n] = bw;
            ldsb1[n]  = sc * (bih1[n] + bhh1[n]);
        }
    }
    __syncthreads();

    const float fcw_l0 = fcw[col];
    const float fcw_l1 = fcw[16 + col];

    // Carried state, SHARED NAMES across roles (keeps cross-barrier live
    // set to ~22 regs): Acur = Ah1(prev) [role 0] or Ah2(prev) [role 1];
    // cv = c1 or c2; fv = fc partials (role 1 only).
    half8 Acur = {};
    floatx2 cv[2][2] = {};
    floatx2 fv[2] = {};

    for (int t = 0; t < TSTEPS; ++t) {
        // Opaque zero offset: keeps weight fragment loads inside the loop.
        unsigned woff = 0;
        asm volatile("" : "+v"(woff));
        const char* wB  = (const char*)ldsw   + lane * 16 + woff;
        const char* bB0 = (const char*)ldsbw0 + col * 8  + woff;
        const char* bB1 = (const char*)ldsb1  + col * 4  + woff;

        if (role == 0) {
            // -------- workA(t): layer-0 gates -> epi0 -> publish h1(t) ----
            _Float16* h1b = &ldsh1[pair][t & 1][0];
            const floatx4 xr = *(const floatx4*)&xl[t * 16 + rg * 4];
            floatx4 g[8];
#pragma unroll
            for (int nt = 0; nt < 8; ++nt) {
                const floatx2 bw = *(const floatx2*)(bB0 + nt * 128);
                const half8 bf   = *(const half8*)(wB + nt * 1024);
                floatx4 c;
#pragma unroll
                for (int r = 0; r < 4; ++r) c[r] = fmaf(bw[1], xr[r], bw[0]);
                // t=0: Acur==0 -> mfma returns c exactly (no special case)
                g[nt] = __builtin_amdgcn_mfma_f32_16x16x32_f16(Acur, bf, c, 0, 0, 0);
            }
#pragma unroll
            for (int q = 0; q < 2; ++q) {
#pragma unroll
                for (int rp = 0; rp < 2; ++rp) {
                    const floatx2 h = cell_pair(
                        mk2(g[0 + q][rp * 2], g[0 + q][rp * 2 + 1]),
                        mk2(g[2 + q][rp * 2], g[2 + q][rp * 2 + 1]),
                        mk2(g[4 + q][rp * 2], g[4 + q][rp * 2 + 1]),
                        mk2(g[6 + q][rp * 2], g[6 + q][rp * 2 + 1]),
                        cv[q][rp]);
                    h1b[(rg * 4 + rp * 2 + 0) * LSTRIDE + q * 16 + col] = (_Float16)h[0];
                    h1b[(rg * 4 + rp * 2 + 1) * LSTRIDE + q * 16 + col] = (_Float16)h[1];
                }
            }
            Acur = *(const half8*)&h1b[col * LSTRIDE + rg * 8];
        }

        __syncthreads();   // h1(t) published; L1 consumes it in this window
                           // while L0 runs workA(t+1) into the other buffer.

        if (role == 1) {
            // -------- workB(t): layer-1 gates -> epi1 -> h2 self-loop -----
            const _Float16* h1b = &ldsh1[pair][t & 1][0];
            const half8 Ah1t = *(const half8*)&h1b[col * LSTRIDE + rg * 8];
            floatx4 g[8];
#pragma unroll
            for (int nt = 0; nt < 8; ++nt) {
                const float b1  = *(const float*)(bB1 + nt * 64);
                const half8 f1a = *(const half8*)(wB + 8192  + nt * 1024);
                const half8 f1b = *(const half8*)(wB + 16384 + nt * 1024);
                floatx4 c = {b1, b1, b1, b1};
                c = __builtin_amdgcn_mfma_f32_16x16x32_f16(Ah1t, f1a, c, 0, 0, 0);
                g[nt] = __builtin_amdgcn_mfma_f32_16x16x32_f16(Acur, f1b, c, 0, 0, 0);
            }
            const float f1t = fc1w[t];
            const float w0 = f1t * fcw_l0;
            const float w1 = f1t * fcw_l1;
#pragma unroll
            for (int q = 0; q < 2; ++q) {
                const float wq = q ? w1 : w0;
                const floatx2 wqv = mk2(wq, wq);
#pragma unroll
                for (int rp = 0; rp < 2; ++rp) {
                    const floatx2 h = cell_pair(
                        mk2(g[0 + q][rp * 2], g[0 + q][rp * 2 + 1]),
                        mk2(g[2 + q][rp * 2], g[2 + q][rp * 2 + 1]),
                        mk2(g[4 + q][rp * 2], g[4 + q][rp * 2 + 1]),
                        mk2(g[6 + q][rp * 2], g[6 + q][rp * 2 + 1]),
                        cv[q][rp]);
                    fv[rp] = __builtin_elementwise_fma(wqv, h, fv[rp]);
                    h2l[(rg * 4 + rp * 2 + 0) * LSTRIDE + q * 16 + col] = (_Float16)h[0];
                    h2l[(rg * 4 + rp * 2 + 1) * LSTRIDE + q * 16 + col] = (_Float16)h[1];
                }
            }
            Acur = *(const half8*)&h2l[col * LSTRIDE + rg * 8];
        }
    }

    // ---- role-1: reduce fc partials across the 16 cols, store ------------
    if (role == 1) {
        float facc[4];
#pragma unroll
        for (int r = 0; r < 4; ++r) facc[r] = fv[r >> 1][r & 1];
#pragma unroll
        for (int r = 0; r < 4; ++r) {
            float v = facc[r];
            v += __shfl_xor(v, 1);
            v += __shfl_xor(v, 2);
            v += __shfl_xor(v, 4);
            v += __shfl_xor(v, 8);
            facc[r] = v;
        }
        float sum_f1 = 0.f;
#pragma unroll
        for (int t = 0; t < TSTEPS; ++t) sum_f1 += fc1w[t];
        const float tail = fcb[0] * sum_f1 + fc1b[0];

        if (col == 0) {
#pragma unroll
            for (int r = 0; r < 4; ++r)
                out[seq_base + rg * 4 + r] = facc[r] + tail;
        }
    }
}

extern "C" void kernel_launch(void* const* d_in, const int* in_sizes, int n_in,
                              void* d_out, int out_size, void* d_ws, size_t ws_size,
                              hipStream_t stream) {
    const float* xin  = (const float*)d_in[0];
    const float* Wih0 = (const float*)d_in[1];
    const float* Whh0 = (const float*)d_in[2];
    const float* bih0 = (const float*)d_in[3];
    const float* bhh0 = (const float*)d_in[4];
    const float* Wih1 = (const float*)d_in[5];
    const float* Whh1 = (const float*)d_in[6];
    const float* bih1 = (const float*)d_in[7];
    const float* bhh1 = (const float*)d_in[8];
    const float* fcw  = (const float*)d_in[9];
    const float* fcb  = (const float*)d_in[10];
    const float* fc1w = (const float*)d_in[11];
    const float* fc1b = (const float*)d_in[12];
    float* out = (float*)d_out;

    const int B = in_sizes[0] / TSTEPS;   // [B, T, F=1]
    const int grid = B / 64;              // 1 block = 4 pairs x 16 seqs
    lstm2_mfma<<<grid, 512, 0, stream>>>(
        xin, Wih0, Whh0, bih0, bhh0, Wih1, Whh1, bih1, bhh1,
        fcw, fcb, fc1w, fc1b, out, B);
}

// Round 17
// 186.605 us; speedup vs baseline: 1.0925x; 1.0925x over previous
//
#include <hip/hip_runtime.h>

// LSTM_52922587021316 — Round 20: wave start-skew (lockstep desync test).
// R19: role-split rejected — barrier-per-t serialized the pair (dur 148,
// stall grew to ~50us); VALU-time ~98us conserved 7 rounds running.
// R15 (129.3us, best) has NO inter-wave dependency, yet VALUBusy=72% at
// 8-waves/SIMD capability. Remaining hypothesis: block waves leave
// __syncthreads IN PHASE and stay there (same code, same latencies), so
// all resident waves hit the recurrence's dependency bubbles simultaneously
// — no off-phase wave to issue from. Fix costs nothing: skew each wave's
// start by wave*512cy via an s_sleep ladder (no regs, no LDS, no numerics;
// ~1.5us avg on a ~80us wave lifetime). Phases in the ~9400cy/t chain are
// 600-2000cy wide -> skews 0.5-3.6Kcy spread 8 waves across the bubbles.
// Cleanest lockstep test: VALUBusy jumps if real; unchanged => bubbles are
// global (every wave starved) and 129us is the structural floor -> ROOFLINE.
// Base: R15 verbatim. Single addition: the skew ladder after staging.

#define HID 32
#define TSTEPS 7
#define LSTRIDE 36   // halves per LDS h-row: 32 + 4 pad (72 B)
#define NWAVES 8     // waves per block

typedef _Float16 half8 __attribute__((ext_vector_type(8)));
typedef float floatx4 __attribute__((ext_vector_type(4)));
typedef float floatx2 __attribute__((ext_vector_type(2)));

#define LOG2E 1.44269504088896f

__device__ __forceinline__ float fast_rcp(float x) { return __builtin_amdgcn_rcpf(x); }

__device__ __forceinline__ float exp2_fast(float x) {
#if __has_builtin(__builtin_amdgcn_exp2f)
    return __builtin_amdgcn_exp2f(x);
#else
    return __expf(x * 0.69314718055994531f);
#endif
}

__device__ __forceinline__ floatx2 mk2(float a, float b) {
    floatx2 v; v[0] = a; v[1] = b; return v;
}
__device__ __forceinline__ floatx2 exp2_v2(floatx2 a) {
    return mk2(exp2_fast(a[0]), exp2_fast(a[1]));
}

// v2.5 cell update on an h-pair (proven absmax 9.77e-4, R11/R13/R15):
// Rb/Rm/Rh pair-batched, c-recurrence sum structure untouched.
__device__ __forceinline__ floatx2 cell_pair(floatx2 gi, floatx2 gf,
                                             floatx2 gg, floatx2 go,
                                             floatx2& cst) {
    const floatx2 one = mk2(1.0f, 1.0f);
    const floatx2 Ea = exp2_v2(gi);
    const floatx2 Db = exp2_v2(gf) + one;
    const floatx2 Ed = exp2_v2(gg);
    const floatx2 Ee = exp2_v2(go);
    const floatx2 M  = (Ea + one) * (Ed + one);
    const float Rb = fast_rcp(Db[0] * Db[1]);
    const float Rm = fast_rcp(M[0] * M[1]);
    const floatx2 ff  = mk2(Rb, Rb) * mk2(Db[1], Db[0]);
    const floatx2 rig = mk2(Rm, Rm) * mk2(M[1], M[0]);
    const floatx2 ig  = __builtin_elementwise_fma(Ed, rig, -rig);
    const floatx2 c   = __builtin_elementwise_fma(ff, cst, ig);
    cst = c;
    const floatx2 Ec  = exp2_v2(c * mk2(2.0f * LOG2E, 2.0f * LOG2E));
    const floatx2 Dh  = (Ee + one) * (Ec + one);
    const float Rh = fast_rcp(Dh[0] * Dh[1]);
    const floatx2 th = mk2(Rh, Rh) * mk2(Dh[1], Dh[0]);
    return __builtin_elementwise_fma(Ec, th, -th);
}

__global__ __launch_bounds__(512, 2) void lstm2_mfma(
    const float* __restrict__ xin,   // [B, 7]
    const float* __restrict__ Wih0,  // [128, 1]
    const float* __restrict__ Whh0,  // [128, 32]
    const float* __restrict__ bih0,  // [128]
    const float* __restrict__ bhh0,  // [128]
    const float* __restrict__ Wih1,  // [128, 32]
    const float* __restrict__ Whh1,  // [128, 32]
    const float* __restrict__ bih1,  // [128]
    const float* __restrict__ bhh1,  // [128]
    const float* __restrict__ fcw,   // [32]
    const float* __restrict__ fcb,   // [1]
    const float* __restrict__ fc1w,  // [7]
    const float* __restrict__ fc1b,  // [1]
    float* __restrict__ out,         // [B]
    int B)
{
    const int lane = threadIdx.x & 63;
    const int wave = threadIdx.x >> 6;
    const int col  = lane & 15;          // C col / A row m
    const int rg   = lane >> 4;          // C rows rg*4..+3 / A k-chunk rg*8..+7
    const int seq_base = (blockIdx.x * NWAVES + wave) * 16;

    // Weight fragments, block-shared, per-lane order:
    // matrix m in {0:Whh0, 1:Wih1, 2:Whh1}, tile nt (0..7), lane, 8 halves.
    // byte offset = m*8192 + nt*1024 + lane*16  -> ds_read_b128, conflict-free.
    __shared__ __align__(16) _Float16 ldsw[3 * 8 * 64 * 8];   // 24 KiB
    __shared__ __align__(16) floatx2  ldsbw0[128];            // {b0s, wx} by n, 1 KiB
    __shared__ float                  ldsb1[128];             // b1s by n, 0.5 KiB
    __shared__ __align__(16) _Float16 ldsh[NWAVES][16 * LSTRIDE];  // ONE h-buffer/wave
    __shared__ __align__(16) float    ldsx[NWAVES][TSTEPS * 16];

    _Float16* hl = &ldsh[wave][0];   // shared by h1 and h2 (same-wave DS in-order)
    float* xl = &ldsx[wave][0];

    // ---- stage x: 112 contiguous floats per wave -> transposed [t][seq] ---
#pragma unroll
    for (int e = lane; e < TSTEPS * 16; e += 64) {
        const int s = e / TSTEPS;
        const int tt = e - s * TSTEPS;
        xl[tt * 16 + s] = xin[seq_base * TSTEPS + e];
    }

    // ---- stage prescaled weights/biases into LDS (once per block) --------
    if (wave < 3) {
        const float* Wsrc = (wave == 0) ? Whh0 : (wave == 1) ? Wih1 : Whh1;
#pragma unroll
        for (int nt = 0; nt < 8; ++nt) {
            const int n = nt * 16 + col;
            const float sc = ((n >> 5) == 2) ? (2.0f * LOG2E) : (-LOG2E);
            const float* s = Wsrc + n * HID + rg * 8;
            half8 f;
#pragma unroll
            for (int j = 0; j < 8; ++j) f[j] = (_Float16)(sc * s[j]);
            *(half8*)&ldsw[((wave * 8 + nt) * 64 + lane) * 8] = f;
        }
    } else if (wave == 3) {
#pragma unroll
        for (int i = 0; i < 2; ++i) {
            const int n = i * 64 + lane;
            const float sc = ((n >> 5) == 2) ? (2.0f * LOG2E) : (-LOG2E);
            floatx2 bw;
            bw[0] = sc * (bih0[n] + bhh0[n]);   // prescaled layer-0 bias
            bw[1] = sc * Wih0[n];               // prescaled rank-1 x weight
            ldsbw0[n] = bw;
            ldsb1[n]  = sc * (bih1[n] + bhh1[n]);
        }
    }
    __syncthreads();

    // ---- START SKEW: desynchronize the block's waves -----------------------
    // wave w sleeps ~w*512cy. Breaks post-barrier phase lock so resident
    // waves hit the recurrence's dependency bubbles at different times.
    for (int i = 0; i < wave; ++i) __builtin_amdgcn_s_sleep(8);

    const float fcw_l0 = fcw[col];
    const float fcw_l1 = fcw[16 + col];

    half8 Ah1 = {};      // h1 in A-layout (zero at t=0)
    half8 Ah2 = {};      // h2 in A-layout
    floatx2 c1v[2][2] = {}, c2v[2][2] = {};   // cell states as pk pairs
    floatx2 faccv[2] = {};                     // fc partials as pk pairs

    for (int t = 0; t < TSTEPS; ++t) {
        // Opaque zero offset: makes the LDS weight addresses loop-variant so
        // LICM cannot hoist the 24 fragment loads back into 96 registers.
        unsigned woff = 0;
        asm volatile("" : "+v"(woff));
        const char* wB  = (const char*)ldsw   + lane * 16 + woff;
        const char* bB0 = (const char*)ldsbw0 + col * 8  + woff;
        const char* bB1 = (const char*)ldsb1  + col * 4  + woff;

        // x for my 4 C-rows (m = rg*4 + r): one b128, conflict-free broadcast
        const floatx4 xr = *(const floatx4*)&xl[t * 16 + rg * 4];

        // -------- layer 0: gates = (bias + x*Wih0) + h1_prev @ Whh0^T -----
        floatx4 g0[8];
#pragma unroll
        for (int nt = 0; nt < 8; ++nt) {
            const floatx2 bw = *(const floatx2*)(bB0 + nt * 128);
            const half8 bf   = *(const half8*)(wB + nt * 1024);
            const floatx2 wv = mk2(bw[1], bw[1]);
            const floatx2 bv = mk2(bw[0], bw[0]);
            const floatx2 clo = __builtin_elementwise_fma(wv, mk2(xr[0], xr[1]), bv);
            const floatx2 chi = __builtin_elementwise_fma(wv, mk2(xr[2], xr[3]), bv);
            floatx4 c;
            c[0] = clo[0]; c[1] = clo[1]; c[2] = chi[0]; c[3] = chi[1];
            g0[nt] = __builtin_amdgcn_mfma_f32_16x16x32_f16(Ah1, bf, c, 0, 0, 0);
        }

        // epilogue 0: packed v2.5 cell update, write h1_new
#pragma unroll
        for (int q = 0; q < 2; ++q) {
#pragma unroll
            for (int rp = 0; rp < 2; ++rp) {
                const floatx2 h = cell_pair(
                    mk2(g0[0 + q][rp * 2], g0[0 + q][rp * 2 + 1]),
                    mk2(g0[2 + q][rp * 2], g0[2 + q][rp * 2 + 1]),
                    mk2(g0[4 + q][rp * 2], g0[4 + q][rp * 2 + 1]),
                    mk2(g0[6 + q][rp * 2], g0[6 + q][rp * 2 + 1]),
                    c1v[q][rp]);
                hl[(rg * 4 + rp * 2 + 0) * LSTRIDE + q * 16 + col] = (_Float16)h[0];
                hl[(rg * 4 + rp * 2 + 1) * LSTRIDE + q * 16 + col] = (_Float16)h[1];
            }
        }
        Ah1 = *(const half8*)&hl[col * LSTRIDE + rg * 8];

        // -------- layer 1: gates = bias + h1_new @ Wih1^T + h2_prev @ Whh1^T
        floatx4 g1[8];
#pragma unroll
        for (int nt = 0; nt < 8; ++nt) {
            const float b1  = *(const float*)(bB1 + nt * 64);
            const half8 f1a = *(const half8*)(wB + 8192  + nt * 1024);
            const half8 f1b = *(const half8*)(wB + 16384 + nt * 1024);
            floatx4 c = {b1, b1, b1, b1};
            c = __builtin_amdgcn_mfma_f32_16x16x32_f16(Ah1, f1a, c, 0, 0, 0);
            g1[nt] = __builtin_amdgcn_mfma_f32_16x16x32_f16(Ah2, f1b, c, 0, 0, 0);
        }

        // epilogue 1: packed v2.5 cell update, fc partial, write h2 over h1
        // (Ah1 already consumed; same-wave DS in-order makes this safe)
        const float f1t = fc1w[t];
        const float w0 = f1t * fcw_l0;
        const float w1 = f1t * fcw_l1;
#pragma unroll
        for (int q = 0; q < 2; ++q) {
            const float wq = q ? w1 : w0;
            const floatx2 wqv = mk2(wq, wq);
#pragma unroll
            for (int rp = 0; rp < 2; ++rp) {
                const floatx2 h = cell_pair(
                    mk2(g1[0 + q][rp * 2], g1[0 + q][rp * 2 + 1]),
                    mk2(g1[2 + q][rp * 2], g1[2 + q][rp * 2 + 1]),
                    mk2(g1[4 + q][rp * 2], g1[4 + q][rp * 2 + 1]),
                    mk2(g1[6 + q][rp * 2], g1[6 + q][rp * 2 + 1]),
                    c2v[q][rp]);
                faccv[rp] = __builtin_elementwise_fma(wqv, h, faccv[rp]);
                hl[(rg * 4 + rp * 2 + 0) * LSTRIDE + q * 16 + col] = (_Float16)h[0];
                hl[(rg * 4 + rp * 2 + 1) * LSTRIDE + q * 16 + col] = (_Float16)h[1];
            }
        }
        Ah2 = *(const half8*)&hl[col * LSTRIDE + rg * 8];
    }

    // ---- reduce fc partials across the 16 cols, add constant tail --------
    float facc[4];
#pragma unroll
    for (int r = 0; r < 4; ++r) facc[r] = faccv[r >> 1][r & 1];
#pragma unroll
    for (int r = 0; r < 4; ++r) {
        float v = facc[r];
        v += __shfl_xor(v, 1);
        v += __shfl_xor(v, 2);
        v += __shfl_xor(v, 4);
        v += __shfl_xor(v, 8);
        facc[r] = v;
    }
    float sum_f1 = 0.f;
#pragma unroll
    for (int t = 0; t < TSTEPS; ++t) sum_f1 += fc1w[t];
    const float tail = fcb[0] * sum_f1 + fc1b[0];

    if (col == 0) {
#pragma unroll
        for (int r = 0; r < 4; ++r)
            out[seq_base + rg * 4 + r] = facc[r] + tail;
    }
}

extern "C" void kernel_launch(void* const* d_in, const int* in_sizes, int n_in,
                              void* d_out, int out_size, void* d_ws, size_t ws_size,
                              hipStream_t stream) {
    const float* xin  = (const float*)d_in[0];
    const float* Wih0 = (const float*)d_in[1];
    const float* Whh0 = (const float*)d_in[2];
    const float* bih0 = (const float*)d_in[3];
    const float* bhh0 = (const float*)d_in[4];
    const float* Wih1 = (const float*)d_in[5];
    const float* Whh1 = (const float*)d_in[6];
    const float* bih1 = (const float*)d_in[7];
    const float* bhh1 = (const float*)d_in[8];
    const float* fcw  = (const float*)d_in[9];
    const float* fcb  = (const float*)d_in[10];
    const float* fc1w = (const float*)d_in[11];
    const float* fc1b = (const float*)d_in[12];
    float* out = (float*)d_out;

    const int B = in_sizes[0] / TSTEPS;       // [B, T, F=1]
    const int grid = B / (NWAVES * 16);       // 1 block = 8 waves = 128 sequences
    lstm2_mfma<<<grid, NWAVES * 64, 0, stream>>>(
        xin, Wih0, Whh0, bih0, bhh0, Wih1, Whh1, bih1, bhh1,
        fcw, fcb, fc1w, fc1b, out, B);
}